// Round 4
// baseline (311.388 us; speedup 1.0000x reference)
//
#include <hip/hip_runtime.h>
#include <math.h>

#define BATCH 256
#define CH 512
#define SE_CH 32
#define HW 1024                       // 32*32
#define CHUNK_B 32                    // 32 batches = 64 MB of x per chunk
#define NCHUNK (BATCH / CHUNK_B)      // 8
#define CHUNK_PLANES (CHUNK_B * CH)   // 16384 planes = 64 MB
#define SUBS 32                       // apply blocks per batch element
#define CPS (CH / SUBS)               // 16 channels per apply block

typedef float f32x4 __attribute__((ext_vector_type(4)));

// Fused pipeline kernel.
//   na = number of apply-role blocks (rest are mean-role).
//   Mixed mode (na>0 and na<grid): even blocks apply, odd blocks mean
//   (parity interleave so both HBM streams flow from dispatch 0).
__global__ __launch_bounds__(256) void se_fused(
        const float* __restrict__ x,
        float* __restrict__ out,
        float* __restrict__ mean_ws,          // [BATCH*CH]
        const float* __restrict__ fc1_w,      // [SE_CH][CH]
        const float* __restrict__ fc1_b,      // [SE_CH]
        const float* __restrict__ fc2_w,      // [2*CH][SE_CH]
        const float* __restrict__ fc2_b,      // [2*CH]
        int na, int apply_b0, int mean_p0, int mean_np) {
    const int t = threadIdx.x;
    const int bid = (int)blockIdx.x;
    const int nm = (int)gridDim.x - na;

    bool is_apply;
    int rid;
    if (na == 0)            { is_apply = false; rid = bid; }
    else if (nm == 0)       { is_apply = true;  rid = bid; }
    else                    { is_apply = !(bid & 1); rid = bid >> 1; }

    if (is_apply) {
        // ---------------- apply role ----------------
        __shared__ float m[CH];
        __shared__ float se[SE_CH];
        __shared__ float sc[CPS];
        __shared__ float bi[CPS];

        const int b = apply_b0 + (rid >> 5);   // batch element
        const int sub = rid & 31;              // 16-channel slice

        for (int i = t; i < CH; i += 256)
            m[i] = mean_ws[(size_t)b * CH + i];
        __syncthreads();

        // FC1: output o = t>>3, partial p = t&7 over k = p+8j (bank-conflict-free)
        {
            const int o = t >> 3;
            const int p = t & 7;
            const float* wr = fc1_w + o * CH;
            float acc = 0.0f;
#pragma unroll
            for (int j = 0; j < 64; ++j) {
                const int k = p + 8 * j;
                acc = fmaf(wr[k], m[k], acc);
            }
            acc += __shfl_xor(acc, 4, 8);
            acc += __shfl_xor(acc, 2, 8);
            acc += __shfl_xor(acc, 1, 8);
            if (p == 0)
                se[o] = fmaxf(acc + fc1_b[o], 0.0f);
        }
        __syncthreads();

        // FC2: this block's 16 scale + 16 bias outputs
        if (t < 2 * CPS) {
            const int c = sub * CPS + (t & (CPS - 1));
            const int o = (t < CPS) ? c : (CH + c);
            float acc = fc2_b[o];
            const float* wr = fc2_w + o * SE_CH;
#pragma unroll
            for (int k = 0; k < SE_CH; ++k)
                acc = fmaf(wr[k], se[k], acc);
            if (t < CPS)
                sc[t] = 1.0f / (1.0f + expf(-acc));
            else
                bi[t - CPS] = acc;
        }
        __syncthreads();

        // apply 16 planes; thread t does f32x4 #t of each plane
        const size_t base = ((size_t)b * CH + (size_t)sub * CPS) * HW;
        const f32x4* xp = (const f32x4*)(x + base);
        f32x4* op = (f32x4*)(out + base);
#pragma unroll 4
        for (int p = 0; p < CPS; ++p) {
            const float s = sc[p];
            const float bb = bi[p];
            f32x4 v = xp[p * 256 + t];
            f32x4 r;
            r.x = fmaf(v.x, s, bb);
            r.y = fmaf(v.y, s, bb);
            r.z = fmaf(v.z, s, bb);
            r.w = fmaf(v.w, s, bb);
            __builtin_nontemporal_store(r, &op[p * 256 + t]);
        }
    } else {
        // ---------------- mean role: 2 planes in flight per wave ----------------
        const int lane = t & 63;
        const int wib = t >> 6;
        const int wid = rid * 4 + wib;
        const int nw = nm * 4;
        for (int p = wid * 2; p < mean_np; p += nw * 2) {
            const f32x4* p0 = (const f32x4*)(x + (size_t)(mean_p0 + p) * HW);
            const f32x4* p1 = (const f32x4*)(x + (size_t)(mean_p0 + p + 1) * HW);
            float s0 = 0.0f, s1 = 0.0f;
#pragma unroll
            for (int j = 0; j < 4; ++j) {
                f32x4 v0 = p0[lane + j * 64];
                f32x4 v1 = p1[lane + j * 64];
                s0 += (v0.x + v0.y) + (v0.z + v0.w);
                s1 += (v1.x + v1.y) + (v1.z + v1.w);
            }
#pragma unroll
            for (int off = 32; off > 0; off >>= 1) {
                s0 += __shfl_down(s0, off, 64);
                s1 += __shfl_down(s1, off, 64);
            }
            if (lane == 0) {
                mean_ws[mean_p0 + p]     = s0 * (1.0f / (float)HW);
                mean_ws[mean_p0 + p + 1] = s1 * (1.0f / (float)HW);
            }
        }
    }
}

extern "C" void kernel_launch(void* const* d_in, const int* in_sizes, int n_in,
                              void* d_out, int out_size, void* d_ws, size_t ws_size,
                              hipStream_t stream) {
    const float* x     = (const float*)d_in[0];
    const float* fc1_w = (const float*)d_in[1];
    const float* fc1_b = (const float*)d_in[2];
    const float* fc2_w = (const float*)d_in[3];
    const float* fc2_b = (const float*)d_in[4];
    float* out = (float*)d_out;
    float* mean = (float*)d_ws;   // BATCH*CH f32

    // Prologue: means of chunk 0 (all blocks mean-role)
    se_fused<<<2048, 256, 0, stream>>>(x, out, mean, fc1_w, fc1_b, fc2_w, fc2_b,
                                       0, 0, 0, CHUNK_PLANES);

    // Steady state: apply(k) + mean(k+1), 1024 blocks each, parity-interleaved
    for (int k = 0; k < NCHUNK - 1; ++k) {
        se_fused<<<2048, 256, 0, stream>>>(
            x, out, mean, fc1_w, fc1_b, fc2_w, fc2_b,
            1024, k * CHUNK_B, (k + 1) * CHUNK_PLANES, CHUNK_PLANES);
    }

    // Epilogue: apply last chunk (all blocks apply-role)
    se_fused<<<1024, 256, 0, stream>>>(
        x, out, mean, fc1_w, fc1_b, fc2_w, fc2_b,
        1024, (NCHUNK - 1) * CHUNK_B, 0, 0);
}

// Round 5
// 260.097 us; speedup vs baseline: 1.1972x; 1.1972x over previous
//
#include <hip/hip_runtime.h>
#include <math.h>

#define BATCH 256
#define CH 512
#define SE_CH 32
#define HW 1024                       // 32*32
#define CHUNK_B 64                    // 64 batches = 128 MB of x per chunk
#define NCHUNK (BATCH / CHUNK_B)      // 4
#define CHUNK_PLANES (CHUNK_B * CH)   // 32768 planes = 128 MB
#define SUBS 16                       // apply blocks per batch element
#define CPS (CH / SUBS)               // 32 channels per apply block
#define NA_BLOCKS (CHUNK_B * SUBS)    // 1024 apply blocks per chunk
#define NM_BLOCKS 1024                // mean-role blocks in fused dispatches

typedef float f32x4 __attribute__((ext_vector_type(4)));

// Fused pipeline kernel, role split by blockIdx (contiguous split keeps both
// roles spread evenly over XCDs since wg->XCD is round-robin).
//   blockIdx < na           : apply chunk at apply_b0 (FC recomputed per block)
//   blockIdx in [na, grid)  : plane means for [mean_p0, mean_p0+mean_np)
//
// Cache discipline: mean reads allocate (future reuse by next dispatch's
// apply); apply reads + out writes are nontemporal (no future reuse) so they
// don't evict the incoming chunk from Infinity Cache.
__global__ __launch_bounds__(256) void se_fused(
        const float* __restrict__ x,
        float* __restrict__ out,
        float* __restrict__ mean_ws,          // [BATCH*CH]
        const float* __restrict__ fc1_w,      // [SE_CH][CH]
        const float* __restrict__ fc1_b,      // [SE_CH]
        const float* __restrict__ fc2_w,      // [2*CH][SE_CH]
        const float* __restrict__ fc2_b,      // [2*CH]
        int na, int apply_b0, int mean_p0, int mean_np) {
    const int t = threadIdx.x;
    const int bid = (int)blockIdx.x;

    if (bid < na) {
        // ---------------- apply role ----------------
        __shared__ float m[CH];
        __shared__ float se[SE_CH];
        __shared__ float sc[CPS];
        __shared__ float bi[CPS];

        const int b = apply_b0 + (bid >> 4);       // batch element
        const int sub = bid & (SUBS - 1);          // 32-channel slice

        for (int i = t; i < CH; i += 256)
            m[i] = mean_ws[(size_t)b * CH + i];
        __syncthreads();

        // FC1: output o = t>>3, partial p = t&7 over k = p+8j (bank-conflict-free)
        {
            const int o = t >> 3;
            const int p = t & 7;
            const float* wr = fc1_w + o * CH;
            float acc = 0.0f;
#pragma unroll
            for (int j = 0; j < 64; ++j) {
                const int k = p + 8 * j;
                acc = fmaf(wr[k], m[k], acc);
            }
            acc += __shfl_xor(acc, 4, 8);
            acc += __shfl_xor(acc, 2, 8);
            acc += __shfl_xor(acc, 1, 8);
            if (p == 0)
                se[o] = fmaxf(acc + fc1_b[o], 0.0f);
        }
        __syncthreads();

        // FC2: this block's 32 scale + 32 bias outputs
        if (t < 2 * CPS) {
            const int c = sub * CPS + (t & (CPS - 1));
            const int o = (t < CPS) ? c : (CH + c);
            float acc = fc2_b[o];
            const float* wr = fc2_w + o * SE_CH;
#pragma unroll
            for (int k = 0; k < SE_CH; ++k)
                acc = fmaf(wr[k], se[k], acc);
            if (t < CPS)
                sc[t] = 1.0f / (1.0f + expf(-acc));
            else
                bi[t - CPS] = acc;
        }
        __syncthreads();

        // apply CPS planes; thread t does f32x4 #t of each plane.
        // Nontemporal loads: last touch of x, don't evict the incoming chunk.
        const size_t base = ((size_t)b * CH + (size_t)sub * CPS) * HW;
        const f32x4* xp = (const f32x4*)(x + base);
        f32x4* op = (f32x4*)(out + base);
#pragma unroll 4
        for (int p = 0; p < CPS; ++p) {
            const float s = sc[p];
            const float bb = bi[p];
            f32x4 v = __builtin_nontemporal_load(&xp[p * 256 + t]);
            f32x4 r;
            r.x = fmaf(v.x, s, bb);
            r.y = fmaf(v.y, s, bb);
            r.z = fmaf(v.z, s, bb);
            r.w = fmaf(v.w, s, bb);
            __builtin_nontemporal_store(r, &op[p * 256 + t]);
        }
    } else {
        // ---------------- mean role: 2 planes in flight per wave ----------------
        // Regular (allocating) loads: this data is re-read by the next
        // dispatch's apply role -> let it populate L3.
        const int lane = t & 63;
        const int wib = t >> 6;
        const int rid = bid - na;
        const int nm = (int)gridDim.x - na;
        const int wid = rid * 4 + wib;
        const int nw = nm * 4;
        for (int p = wid * 2; p < mean_np; p += nw * 2) {
            const f32x4* p0 = (const f32x4*)(x + (size_t)(mean_p0 + p) * HW);
            const f32x4* p1 = (const f32x4*)(x + (size_t)(mean_p0 + p + 1) * HW);
            float s0 = 0.0f, s1 = 0.0f;
#pragma unroll
            for (int j = 0; j < 4; ++j) {
                f32x4 v0 = p0[lane + j * 64];
                f32x4 v1 = p1[lane + j * 64];
                s0 += (v0.x + v0.y) + (v0.z + v0.w);
                s1 += (v1.x + v1.y) + (v1.z + v1.w);
            }
#pragma unroll
            for (int off = 32; off > 0; off >>= 1) {
                s0 += __shfl_down(s0, off, 64);
                s1 += __shfl_down(s1, off, 64);
            }
            if (lane == 0) {
                mean_ws[mean_p0 + p]     = s0 * (1.0f / (float)HW);
                mean_ws[mean_p0 + p + 1] = s1 * (1.0f / (float)HW);
            }
        }
    }
}

extern "C" void kernel_launch(void* const* d_in, const int* in_sizes, int n_in,
                              void* d_out, int out_size, void* d_ws, size_t ws_size,
                              hipStream_t stream) {
    const float* x     = (const float*)d_in[0];
    const float* fc1_w = (const float*)d_in[1];
    const float* fc1_b = (const float*)d_in[2];
    const float* fc2_w = (const float*)d_in[3];
    const float* fc2_b = (const float*)d_in[4];
    float* out = (float*)d_out;
    float* mean = (float*)d_ws;   // BATCH*CH f32

    // Prologue: means of chunk 0, full machine.
    se_fused<<<2048, 256, 0, stream>>>(x, out, mean, fc1_w, fc1_b, fc2_w, fc2_b,
                                       0, 0, 0, CHUNK_PLANES);

    // Steady state: apply(k) (1024 blocks) + mean(k+1) (1024 blocks).
    for (int k = 0; k < NCHUNK - 1; ++k) {
        se_fused<<<NA_BLOCKS + NM_BLOCKS, 256, 0, stream>>>(
            x, out, mean, fc1_w, fc1_b, fc2_w, fc2_b,
            NA_BLOCKS, k * CHUNK_B, (k + 1) * CHUNK_PLANES, CHUNK_PLANES);
    }

    // Epilogue: apply last chunk (all blocks apply-role).
    se_fused<<<NA_BLOCKS, 256, 0, stream>>>(
        x, out, mean, fc1_w, fc1_b, fc2_w, fc2_b,
        NA_BLOCKS, (NCHUNK - 1) * CHUNK_B, 0, 0);
}